// Round 6
// baseline (342.485 us; speedup 1.0000x reference)
//
#include <hip/hip_runtime.h>
#include <hip/hip_bf16.h>

// Problem constants: N=20000 nodes, K=32 nbrs, C=128, H=256
#define NN    20000
#define KNN   32
#define CIN   128
#define HD    256
#define EE    (NN * KNN)        // 640000 edges
#define MT    64                // edge rows per tile = 2 full nodes
#define TPB   10                // tiles per block
#define NBLK  (EE / (MT * TPB)) // 1000 blocks

typedef __bf16 bf16x8_t __attribute__((ext_vector_type(8)));
typedef __bf16 bf16x4_t __attribute__((ext_vector_type(4)));
typedef float  f32x4_t  __attribute__((ext_vector_type(4)));

// Prep:
//  (a) nfb = bf16(nf)
//  (b) w1g = frag-ordered W1' where W1' = [W1a-W1b ; W1b]
//      chunk (kt,qr): w1g[((kt*4+qr)*256+n)*8+j] = W1'[k=kt*32+qr*8+j][n]
//  (c) w2t[n*256+k] = bf16(W2[k][n])
__global__ void ec_prep(const float* __restrict__ nf, const float* __restrict__ W1,
                        const float* __restrict__ W2, __bf16* __restrict__ nfb,
                        __bf16* __restrict__ w1g, __bf16* __restrict__ w2t) {
    int bid = blockIdx.x;
    if (bid < (NN * CIN) / 256) {
        int i = bid * 256 + threadIdx.x;
        nfb[i] = (__bf16)nf[i];
    } else {
        int idx = (bid - (NN * CIN) / 256) * 256 + threadIdx.x;   // 0..65535
        int k = idx >> 8, n = idx & 255;
        float v = (k < CIN) ? (W1[k * 256 + n] - W1[(k + CIN) * 256 + n])
                            : W1[k * 256 + n];
        int kt = k >> 5, qr = (k >> 3) & 3, j = k & 7;
        w1g[(size_t)((kt * 4 + qr) * 256 + n) * 8 + j] = (__bf16)v;
        w2t[n * 256 + k] = (__bf16)W2[k * 256 + n];
    }
}

// R5 structure (weight-stationary, E direct-to-register, H-only LDS round-trip)
// but 512 threads / 8 waves: each wave owns a 32-feature slice -> half the
// per-wave registers -> 2 waves/SIMD co-resident for latency hiding.
__global__ __launch_bounds__(512, 2) void ec_main(
    const __bf16* __restrict__ nfb,      // [NN][CIN] bf16
    const int*   __restrict__ senders,   // [EE]
    const __bf16* __restrict__ w1g,      // frag-ordered W1' (65536)
    const __bf16* __restrict__ w2t,      // [256 n][256 k]
    const float* __restrict__ b1,
    const float* __restrict__ b2,
    float* __restrict__ out)             // [NN][HD] fp32
{
    __shared__ __attribute__((aligned(16))) __bf16 ldsW1[57344];  // 112 KB: kt 1..7
    __shared__ __attribute__((aligned(16))) __bf16 ldsH[16384];   // 32 KB frag-ordered H

    const int tid  = threadIdx.x;
    const int lane = tid & 63;
    const int wave = tid >> 6;           // 0..7 -> feature slice wave*32
    const int qrow = lane >> 4;
    const int lcol = lane & 15;
    const int blk  = blockIdx.x;
    const int fsl  = wave * 32;

    // ---- copy frag-ordered W1' chunks kt=1..7 into LDS (114688 B contiguous) ----
    {
        const float4* src = (const float4*)(w1g + 8192);
        float4* dst = (float4*)ldsW1;
#pragma unroll
        for (int i = 0; i < 14; ++i)
            dst[i * 512 + tid] = src[i * 512 + tid];
    }

    // ---- register-resident weights (per-wave 32-feature slice) ----
    bf16x8_t w10[2];                       // W1' kt=0
#pragma unroll
    for (int mi = 0; mi < 2; ++mi)
        w10[mi] = *(const bf16x8_t*)(w1g + (size_t)(qrow * 256 + fsl + mi * 16 + lcol) * 8);

    bf16x8_t w2f[8][2];                    // W2 slice: 64 VGPRs
#pragma unroll
    for (int kt = 0; kt < 8; ++kt)
#pragma unroll
        for (int ni = 0; ni < 2; ++ni)
            w2f[kt][ni] = *(const bf16x8_t*)(w2t + (size_t)(fsl + ni * 16 + lcol) * 256
                                                 + kt * 32 + qrow * 8);

    float4 bias1[2];
#pragma unroll
    for (int mi = 0; mi < 2; ++mi)
        bias1[mi] = *(const float4*)(b1 + fsl + mi * 16 + qrow * 4);
    float bias2[2];
#pragma unroll
    for (int ni = 0; ni < 2; ++ni)
        bias2[ni] = b2[fsl + ni * 16 + lcol];

    // ---- tile-0 sender indices + sender fragments (B-frag, k-half 128..255) ----
    int sidx[4];
#pragma unroll
    for (int ni = 0; ni < 4; ++ni)
        sidx[ni] = senders[blk * TPB * MT + ni * 16 + lcol];
    bf16x8_t sf[4][4];                     // [edge-group][kt-4]
#pragma unroll
    for (int ni = 0; ni < 4; ++ni)
#pragma unroll
        for (int c = 0; c < 4; ++c)
            sf[ni][c] = *(const bf16x8_t*)(nfb + (size_t)sidx[ni] * CIN + c * 32 + qrow * 8);

    __syncthreads();   // ldsW1 ready

#pragma unroll 1
    for (int t = 0; t < TPB; ++t) {
        const int node0 = (blk * TPB + t) * 2;

        // early-issue next tile's sender indices
        const int tn = (t + 1 < TPB) ? t + 1 : t;
        int nsidx[4];
#pragma unroll
        for (int ni = 0; ni < 4; ++ni)
            nsidx[ni] = senders[(blk * TPB + tn) * MT + ni * 16 + lcol];

        // receiver fragments kt 0..3: lane-broadcast (edges of a node share x_v)
        bf16x8_t efr[2][4];
#pragma unroll
        for (int nd = 0; nd < 2; ++nd)
#pragma unroll
            for (int c = 0; c < 4; ++c)
                efr[nd][c] = *(const bf16x8_t*)(nfb + (size_t)(node0 + nd) * CIN + c * 32 + qrow * 8);

        // ---- GEMM1 (swapped): D = W1'slice · E'^T ; acc[2 feat-groups][4 edge-groups] ----
        f32x4_t acc[2][4];
#pragma unroll
        for (int mi = 0; mi < 2; ++mi)
#pragma unroll
            for (int ni = 0; ni < 4; ++ni)
                acc[mi][ni] = (f32x4_t){0.f, 0.f, 0.f, 0.f};

        // kt = 0: W1 from registers
#pragma unroll
        for (int mi = 0; mi < 2; ++mi)
#pragma unroll
            for (int ni = 0; ni < 4; ++ni)
                acc[mi][ni] = __builtin_amdgcn_mfma_f32_16x16x32_bf16(
                    w10[mi], efr[ni >> 1][0], acc[mi][ni], 0, 0, 0);
        // kt = 1..3: W1 from LDS, E = receiver broadcast
#pragma unroll
        for (int kt = 1; kt < 4; ++kt) {
            bf16x8_t wf[2];
#pragma unroll
            for (int mi = 0; mi < 2; ++mi)
                wf[mi] = *(const bf16x8_t*)(ldsW1 +
                    (size_t)(((kt - 1) * 4 + qrow) * 256 + fsl + mi * 16 + lcol) * 8);
#pragma unroll
            for (int mi = 0; mi < 2; ++mi)
#pragma unroll
                for (int ni = 0; ni < 4; ++ni)
                    acc[mi][ni] = __builtin_amdgcn_mfma_f32_16x16x32_bf16(
                        wf[mi], efr[ni >> 1][kt], acc[mi][ni], 0, 0, 0);
        }
        // kt = 4..7: W1 from LDS, E = prefetched sender fragments
#pragma unroll
        for (int kt = 4; kt < 8; ++kt) {
            bf16x8_t wf[2];
#pragma unroll
            for (int mi = 0; mi < 2; ++mi)
                wf[mi] = *(const bf16x8_t*)(ldsW1 +
                    (size_t)(((kt - 1) * 4 + qrow) * 256 + fsl + mi * 16 + lcol) * 8);
#pragma unroll
            for (int mi = 0; mi < 2; ++mi)
#pragma unroll
                for (int ni = 0; ni < 4; ++ni)
                    acc[mi][ni] = __builtin_amdgcn_mfma_f32_16x16x32_bf16(
                        wf[mi], sf[ni][kt - 4], acc[mi][ni], 0, 0, 0);
        }

        __syncthreads();   // barrier A: previous tile's GEMM2 done reading ldsH

        // ---- epilogue 1: +b1, relu, packed bf16x4 -> ldsH (frag-ordered) ----
#pragma unroll
        for (int mi = 0; mi < 2; ++mi) {
            const int f0  = fsl + mi * 16 + qrow * 4;
            const int ktp = f0 >> 5, qrp = (f0 >> 3) & 3, jh = f0 & 7;
            float4 bb = bias1[mi];
#pragma unroll
            for (int ni = 0; ni < 4; ++ni) {
                int edge = ni * 16 + lcol;
                float v0 = acc[mi][ni][0] + bb.x;
                float v1 = acc[mi][ni][1] + bb.y;
                float v2 = acc[mi][ni][2] + bb.z;
                float v3 = acc[mi][ni][3] + bb.w;
                bf16x4_t h = { (__bf16)fmaxf(v0, 0.f), (__bf16)fmaxf(v1, 0.f),
                               (__bf16)fmaxf(v2, 0.f), (__bf16)fmaxf(v3, 0.f) };
                *(bf16x4_t*)(ldsH + (size_t)((ktp * 4 + qrp) * 64 + edge) * 8 + jh) = h;
            }
        }
        __syncthreads();   // barrier B: ldsH ready

        // ---- prefetch next tile's sender fragments (drain during GEMM2) ----
        bf16x8_t sfn[4][4];
#pragma unroll
        for (int ni = 0; ni < 4; ++ni)
#pragma unroll
            for (int c = 0; c < 4; ++c)
                sfn[ni][c] = *(const bf16x8_t*)(nfb + (size_t)nsidx[ni] * CIN + c * 32 + qrow * 8);

        // ---- GEMM2 (unswapped): D = H · W2slice ; pure LDS + registers ----
        f32x4_t acc2[4][2];
#pragma unroll
        for (int mi = 0; mi < 4; ++mi)
#pragma unroll
            for (int ni = 0; ni < 2; ++ni)
                acc2[mi][ni] = (f32x4_t){0.f, 0.f, 0.f, 0.f};
#pragma unroll
        for (int kt = 0; kt < 8; ++kt) {
            bf16x8_t af[4];
#pragma unroll
            for (int mi = 0; mi < 4; ++mi)
                af[mi] = *(const bf16x8_t*)(ldsH +
                    (size_t)((kt * 4 + qrow) * 64 + mi * 16 + lcol) * 8);
#pragma unroll
            for (int mi = 0; mi < 4; ++mi)
#pragma unroll
                for (int ni = 0; ni < 2; ++ni)
                    acc2[mi][ni] = __builtin_amdgcn_mfma_f32_16x16x32_bf16(
                        af[mi], w2f[kt][ni], acc2[mi][ni], 0, 0, 0);
        }

        // ---- epilogue 2: per-node max over 32 edge rows, +b2, store ----
#pragma unroll
        for (int ni = 0; ni < 2; ++ni) {
            int col = fsl + ni * 16 + lcol;
#pragma unroll
            for (int nd = 0; nd < 2; ++nd) {
                float mx = -3.402823466e38f;
#pragma unroll
                for (int h = 0; h < 2; ++h)
#pragma unroll
                    for (int r = 0; r < 4; ++r)
                        mx = fmaxf(mx, acc2[nd * 2 + h][ni][r]);
                mx = fmaxf(mx, __shfl_xor(mx, 16, 64));
                mx = fmaxf(mx, __shfl_xor(mx, 32, 64));
                if (qrow == 0)
                    out[(size_t)(node0 + nd) * HD + col] = mx + bias2[ni];
            }
        }

        // rotate prefetch
#pragma unroll
        for (int ni = 0; ni < 4; ++ni) {
            sidx[ni] = nsidx[ni];
#pragma unroll
            for (int c = 0; c < 4; ++c)
                sf[ni][c] = sfn[ni][c];
        }
    }
}

extern "C" void kernel_launch(void* const* d_in, const int* in_sizes, int n_in,
                              void* d_out, int out_size, void* d_ws, size_t ws_size,
                              hipStream_t stream) {
    const float* nf      = (const float*)d_in[0];
    const int*   senders = (const int*)d_in[1];
    // d_in[2] = receivers: implicit (repeat(arange(N), K)), unused
    const float* W1 = (const float*)d_in[3];
    const float* b1 = (const float*)d_in[4];
    const float* W2 = (const float*)d_in[5];
    const float* b2 = (const float*)d_in[6];

    __bf16* w1g = (__bf16*)d_ws;                 // 128 KB frag-ordered W1'
    __bf16* w2t = w1g + 256 * 256;               // 128 KB
    __bf16* nfb = w2t + 256 * 256;               // 5.12 MB bf16 node features

    ec_prep<<<(NN * CIN) / 256 + 256, 256, 0, stream>>>(nf, W1, W2, nfb, w1g, w2t);
    ec_main<<<NBLK, 512, 0, stream>>>(nfb, senders, w1g, w2t, b1, b2, (float*)d_out);
}

// Round 7
// 240.078 us; speedup vs baseline: 1.4266x; 1.4266x over previous
//
#include <hip/hip_runtime.h>
#include <hip/hip_bf16.h>

// Problem constants: N=20000 nodes, K=32 nbrs, C=128, H=256
#define NN    20000
#define KNN   32
#define CIN   128
#define HD    256
#define EE    (NN * KNN)        // 640000 edges
#define MT    64                // edge rows per tile = 2 full nodes
#define TPB   10                // tiles per block
#define NBLK  (EE / (MT * TPB)) // 1000 blocks

typedef __bf16 bf16x8_t __attribute__((ext_vector_type(8)));
typedef __bf16 bf16x4_t __attribute__((ext_vector_type(4)));
typedef float  f32x4_t  __attribute__((ext_vector_type(4)));

// async global->LDS, 16B per lane; LDS dest = uniform base + lane*16
__device__ __forceinline__ void gload_lds16(const __bf16* g, __bf16* l) {
    __builtin_amdgcn_global_load_lds(
        (const __attribute__((address_space(1))) void*)g,
        (__attribute__((address_space(3))) void*)l, 16, 0, 0);
}

// Prep:
//  (a) nfb = bf16(nf)
//  (b) w1g = frag-ordered W1' where W1' = [W1a-W1b ; W1b]
//      w1g[((kt*4+qr)*256+n)*8+j] = W1'[k=kt*32+qr*8+j][n]
//  (c) w2t[n*256+k] = bf16(W2[k][n])
__global__ void ec_prep(const float* __restrict__ nf, const float* __restrict__ W1,
                        const float* __restrict__ W2, __bf16* __restrict__ nfb,
                        __bf16* __restrict__ w1g, __bf16* __restrict__ w2t) {
    int bid = blockIdx.x;
    if (bid < (NN * CIN) / 256) {
        int i = bid * 256 + threadIdx.x;
        nfb[i] = (__bf16)nf[i];
    } else {
        int idx = (bid - (NN * CIN) / 256) * 256 + threadIdx.x;   // 0..65535
        int k = idx >> 8, n = idx & 255;
        float v = (k < CIN) ? (W1[k * 256 + n] - W1[(k + CIN) * 256 + n])
                            : W1[k * 256 + n];
        int kt = k >> 5, qr = (k >> 3) & 3, j = k & 7;
        w1g[(size_t)((kt * 4 + qr) * 256 + n) * 8 + j] = (__bf16)v;
        w2t[n * 256 + k] = (__bf16)W2[k * 256 + n];
    }
}

// 512 thr / 8 waves, 1 block/CU. W1' kt0-1 + W2-slice in regs, W1' kt2-7 in LDS.
// Sender E staged via global_load_lds into frag-ordered ldsE (2 instr/wave/tile),
// receiver E prefetched one tile ahead in regs. H round-trips 32KB frag-ordered LDS.
__global__ __launch_bounds__(512, 1) void ec_main(
    const __bf16* __restrict__ nfb,      // [NN][CIN] bf16
    const int*   __restrict__ senders,   // [EE]
    const __bf16* __restrict__ w1g,      // frag-ordered W1'
    const __bf16* __restrict__ w2t,      // [256 n][256 k]
    const float* __restrict__ b1,
    const float* __restrict__ b2,
    float* __restrict__ out)             // [NN][HD] fp32
{
    __shared__ __attribute__((aligned(16))) __bf16 ldsW[49152];  // 96 KB: W1' kt2..7
    __shared__ __attribute__((aligned(16))) __bf16 ldsE[8192];   // 16 KB: sender half, frag-ordered
    __shared__ __attribute__((aligned(16))) __bf16 ldsH[16384];  // 32 KB: H, frag-ordered

    const int tid  = threadIdx.x;
    const int lane = tid & 63;
    const int wave = tid >> 6;           // 0..7 -> feature slice wave*32
    const int qrow = lane >> 4;
    const int lcol = lane & 15;
    const int blk  = blockIdx.x;
    const int fsl  = wave * 32;
    // staging pair ids for this wave: pair = c*4 + qr  (c = k-chunk, qr = quad)
    const int p0 = wave * 2, p1 = wave * 2 + 1;
    const int c0 = p0 >> 2, q0 = p0 & 3;
    const int c1 = p1 >> 2, q1 = p1 & 3;

    // ---- copy W1' kt2..7 into ldsW (96 KB contiguous) ----
    {
        const float4* src = (const float4*)(w1g + 16384);
        float4* dst = (float4*)ldsW;
#pragma unroll
        for (int i = 0; i < 12; ++i)
            dst[i * 512 + tid] = src[i * 512 + tid];
    }

    // ---- register-resident weights ----
    bf16x8_t w1r[2][2];                    // W1' kt=0,1 (16 VGPRs)
#pragma unroll
    for (int kt = 0; kt < 2; ++kt)
#pragma unroll
        for (int mi = 0; mi < 2; ++mi)
            w1r[kt][mi] = *(const bf16x8_t*)(w1g +
                (size_t)((kt * 4 + qrow) * 256 + fsl + mi * 16 + lcol) * 8);

    bf16x8_t w2f[8][2];                    // W2 slice (64 VGPRs)
#pragma unroll
    for (int kt = 0; kt < 8; ++kt)
#pragma unroll
        for (int ni = 0; ni < 2; ++ni)
            w2f[kt][ni] = *(const bf16x8_t*)(w2t + (size_t)(fsl + ni * 16 + lcol) * 256
                                                 + kt * 32 + qrow * 8);

    float4 bias1[2];
#pragma unroll
    for (int mi = 0; mi < 2; ++mi)
        bias1[mi] = *(const float4*)(b1 + fsl + mi * 16 + qrow * 4);
    float bias2[2];
#pragma unroll
    for (int ni = 0; ni < 2; ++ni)
        bias2[ni] = b2[fsl + ni * 16 + lcol];

    // ---- tile 0: stage sender half into ldsE + receiver frags into regs ----
    {
        int sidx = senders[blk * TPB * MT + lane];            // lane = edge
        gload_lds16(nfb + (size_t)sidx * CIN + c0 * 32 + q0 * 8, ldsE + p0 * 512);
        gload_lds16(nfb + (size_t)sidx * CIN + c1 * 32 + q1 * 8, ldsE + p1 * 512);
    }
    bf16x8_t efr[2][4];                    // receiver frags, tile t (32 VGPRs)
    {
        int node0 = blk * TPB * 2;
#pragma unroll
        for (int nd = 0; nd < 2; ++nd)
#pragma unroll
            for (int c = 0; c < 4; ++c)
                efr[nd][c] = *(const bf16x8_t*)(nfb + (size_t)(node0 + nd) * CIN + c * 32 + qrow * 8);
    }
    __syncthreads();   // ldsW + ldsE(t0) ready (vmcnt drained per wave)

#pragma unroll 1
    for (int t = 0; t < TPB; ++t) {
        const int node0 = (blk * TPB + t) * 2;
        const bool more = (t + 1 < TPB);

        // sender indices for tile t+1 (result needed after barrier A)
        int sidxN = 0;
        if (more) sidxN = senders[(blk * TPB + t + 1) * MT + lane];

        // ---- GEMM1 (swapped): D = W1'slice · E'^T ; acc[2 feat][4 edge] ----
        f32x4_t acc[2][4];
#pragma unroll
        for (int mi = 0; mi < 2; ++mi)
#pragma unroll
            for (int ni = 0; ni < 4; ++ni)
                acc[mi][ni] = (f32x4_t){0.f, 0.f, 0.f, 0.f};

        // kt 0..1: W from regs, E = receiver broadcast
#pragma unroll
        for (int kt = 0; kt < 2; ++kt)
#pragma unroll
            for (int mi = 0; mi < 2; ++mi)
#pragma unroll
                for (int ni = 0; ni < 4; ++ni)
                    acc[mi][ni] = __builtin_amdgcn_mfma_f32_16x16x32_bf16(
                        w1r[kt][mi], efr[ni >> 1][kt], acc[mi][ni], 0, 0, 0);
        // kt 2..3: W from ldsW, E = receiver broadcast
#pragma unroll
        for (int kt = 2; kt < 4; ++kt) {
            bf16x8_t wf[2];
#pragma unroll
            for (int mi = 0; mi < 2; ++mi)
                wf[mi] = *(const bf16x8_t*)(ldsW +
                    (size_t)(((kt - 2) * 4 + qrow) * 256 + fsl + mi * 16 + lcol) * 8);
#pragma unroll
            for (int mi = 0; mi < 2; ++mi)
#pragma unroll
                for (int ni = 0; ni < 4; ++ni)
                    acc[mi][ni] = __builtin_amdgcn_mfma_f32_16x16x32_bf16(
                        wf[mi], efr[ni >> 1][kt], acc[mi][ni], 0, 0, 0);
        }
        // kt 4..7: W from ldsW, E = staged sender frags from ldsE
#pragma unroll
        for (int kt = 4; kt < 8; ++kt) {
            bf16x8_t wf[2], ef[4];
#pragma unroll
            for (int mi = 0; mi < 2; ++mi)
                wf[mi] = *(const bf16x8_t*)(ldsW +
                    (size_t)(((kt - 2) * 4 + qrow) * 256 + fsl + mi * 16 + lcol) * 8);
#pragma unroll
            for (int ni = 0; ni < 4; ++ni)
                ef[ni] = *(const bf16x8_t*)(ldsE +
                    (size_t)(((kt - 4) * 4 + qrow) * 64 + ni * 16 + lcol) * 8);
#pragma unroll
            for (int mi = 0; mi < 2; ++mi)
#pragma unroll
                for (int ni = 0; ni < 4; ++ni)
                    acc[mi][ni] = __builtin_amdgcn_mfma_f32_16x16x32_bf16(
                        wf[mi], ef[ni], acc[mi][ni], 0, 0, 0);
        }

        __syncthreads();   // barrier A: ldsE(t) reads + ldsH(t-1) reads done

        // ---- stage tile t+1: sender -> ldsE (async), receiver -> regs ----
        bf16x8_t efrN[2][4];
        if (more) {
            gload_lds16(nfb + (size_t)sidxN * CIN + c0 * 32 + q0 * 8, ldsE + p0 * 512);
            gload_lds16(nfb + (size_t)sidxN * CIN + c1 * 32 + q1 * 8, ldsE + p1 * 512);
            int nn0 = node0 + 2;
#pragma unroll
            for (int nd = 0; nd < 2; ++nd)
#pragma unroll
                for (int c = 0; c < 4; ++c)
                    efrN[nd][c] = *(const bf16x8_t*)(nfb + (size_t)(nn0 + nd) * CIN + c * 32 + qrow * 8);
        }

        // ---- epilogue 1: +b1, relu, packed bf16x4 -> ldsH (frag-ordered) ----
#pragma unroll
        for (int mi = 0; mi < 2; ++mi) {
            const int f0  = fsl + mi * 16 + qrow * 4;
            const int ktp = f0 >> 5, qrp = (f0 >> 3) & 3, jh = f0 & 7;
            float4 bb = bias1[mi];
#pragma unroll
            for (int ni = 0; ni < 4; ++ni) {
                int edge = ni * 16 + lcol;
                float v0 = acc[mi][ni][0] + bb.x;
                float v1 = acc[mi][ni][1] + bb.y;
                float v2 = acc[mi][ni][2] + bb.z;
                float v3 = acc[mi][ni][3] + bb.w;
                bf16x4_t h = { (__bf16)fmaxf(v0, 0.f), (__bf16)fmaxf(v1, 0.f),
                               (__bf16)fmaxf(v2, 0.f), (__bf16)fmaxf(v3, 0.f) };
                *(bf16x4_t*)(ldsH + (size_t)((ktp * 4 + qrp) * 64 + edge) * 8 + jh) = h;
            }
        }
        __syncthreads();   // barrier B: ldsH ready; ldsE(t+1) staged & visible

        // ---- GEMM2 (unswapped): D = H · W2slice ; pure LDS + registers ----
        f32x4_t acc2[4][2];
#pragma unroll
        for (int mi = 0; mi < 4; ++mi)
#pragma unroll
            for (int ni = 0; ni < 2; ++ni)
                acc2[mi][ni] = (f32x4_t){0.f, 0.f, 0.f, 0.f};
#pragma unroll
        for (int kt = 0; kt < 8; ++kt) {
            bf16x8_t af[4];
#pragma unroll
            for (int mi = 0; mi < 4; ++mi)
                af[mi] = *(const bf16x8_t*)(ldsH +
                    (size_t)((kt * 4 + qrow) * 64 + mi * 16 + lcol) * 8);
#pragma unroll
            for (int mi = 0; mi < 4; ++mi)
#pragma unroll
                for (int ni = 0; ni < 2; ++ni)
                    acc2[mi][ni] = __builtin_amdgcn_mfma_f32_16x16x32_bf16(
                        af[mi], w2f[kt][ni], acc2[mi][ni], 0, 0, 0);
        }

        // ---- epilogue 2: per-node max over 32 edge rows, +b2, store ----
#pragma unroll
        for (int ni = 0; ni < 2; ++ni) {
            int col = fsl + ni * 16 + lcol;
#pragma unroll
            for (int nd = 0; nd < 2; ++nd) {
                float mx = -3.402823466e38f;
#pragma unroll
                for (int h = 0; h < 2; ++h)
#pragma unroll
                    for (int r = 0; r < 4; ++r)
                        mx = fmaxf(mx, acc2[nd * 2 + h][ni][r]);
                mx = fmaxf(mx, __shfl_xor(mx, 16, 64));
                mx = fmaxf(mx, __shfl_xor(mx, 32, 64));
                if (qrow == 0)
                    out[(size_t)(node0 + nd) * HD + col] = mx + bias2[ni];
            }
        }

        // rotate receiver prefetch
        if (more) {
#pragma unroll
            for (int nd = 0; nd < 2; ++nd)
#pragma unroll
                for (int c = 0; c < 4; ++c)
                    efr[nd][c] = efrN[nd][c];
        }
    }
}

extern "C" void kernel_launch(void* const* d_in, const int* in_sizes, int n_in,
                              void* d_out, int out_size, void* d_ws, size_t ws_size,
                              hipStream_t stream) {
    const float* nf      = (const float*)d_in[0];
    const int*   senders = (const int*)d_in[1];
    // d_in[2] = receivers: implicit (repeat(arange(N), K)), unused
    const float* W1 = (const float*)d_in[3];
    const float* b1 = (const float*)d_in[4];
    const float* W2 = (const float*)d_in[5];
    const float* b2 = (const float*)d_in[6];

    __bf16* w1g = (__bf16*)d_ws;                 // 128 KB frag-ordered W1'
    __bf16* w2t = w1g + 256 * 256;               // 128 KB
    __bf16* nfb = w2t + 256 * 256;               // 5.12 MB bf16 node features

    ec_prep<<<(NN * CIN) / 256 + 256, 256, 0, stream>>>(nf, W1, W2, nfb, w1g, w2t);
    ec_main<<<NBLK, 512, 0, stream>>>(nfb, senders, w1g, w2t, b1, b2, (float*)d_out);
}

// Round 8
// 230.113 us; speedup vs baseline: 1.4883x; 1.0433x over previous
//
#include <hip/hip_runtime.h>
#include <hip/hip_bf16.h>

// Problem constants: N=20000 nodes, K=32 nbrs, C=128, H=256
#define NN    20000
#define KNN   32
#define CIN   128
#define HD    256
#define EE    (NN * KNN)        // 640000 edges
#define MT    64                // edge rows per tile = 2 full nodes
#define TPB   10                // tiles per block -> 20 nodes per block
#define NBLK  (EE / (MT * TPB)) // 1000 blocks

typedef __bf16 bf16x8_t __attribute__((ext_vector_type(8)));
typedef __bf16 bf16x4_t __attribute__((ext_vector_type(4)));
typedef float  f32x4_t  __attribute__((ext_vector_type(4)));

// async global->LDS, 16B per lane; LDS dest = uniform base + lane*16
__device__ __forceinline__ void gload_lds16(const __bf16* g, __bf16* l) {
    __builtin_amdgcn_global_load_lds(
        (const __attribute__((address_space(1))) void*)g,
        (__attribute__((address_space(3))) void*)l, 16, 0, 0);
}

// Prep:
//  (a) nfb = bf16(nf)  (float4-vectorized)
//  (b) w1g = frag-ordered W1' where W1' = [W1a-W1b ; W1b]
//      w1g[((kt*4+qr)*256+n)*8+j] = W1'[k=kt*32+qr*8+j][n]
//      (h1 = x_v*(W1a-W1b) + x_vp*W1b; kt0-3 = receiver half, kt4-7 = sender half)
//  (c) w2t[n*256+k] = bf16(W2[k][n])
__global__ void ec_prep(const float* __restrict__ nf, const float* __restrict__ W1,
                        const float* __restrict__ W2, __bf16* __restrict__ nfb,
                        __bf16* __restrict__ w1g, __bf16* __restrict__ w2t) {
    int bid = blockIdx.x;
    if (bid < (NN * CIN) / 1024) {                  // 2500 blocks: nf cast, 4 elems/thread
        int i = (bid * 256 + threadIdx.x) * 4;
        float4 v = *(const float4*)(nf + i);
        bf16x4_t b = { (__bf16)v.x, (__bf16)v.y, (__bf16)v.z, (__bf16)v.w };
        *(bf16x4_t*)(nfb + i) = b;
    } else {                                        // 256 blocks: weights
        int idx = (bid - (NN * CIN) / 1024) * 256 + threadIdx.x;   // 0..65535
        int k = idx >> 8, n = idx & 255;
        float v = (k < CIN) ? (W1[k * 256 + n] - W1[(k + CIN) * 256 + n])
                            : W1[k * 256 + n];
        int kt = k >> 5, qr = (k >> 3) & 3, j = k & 7;
        w1g[(size_t)((kt * 4 + qr) * 256 + n) * 8 + j] = (__bf16)v;
        w2t[n * 256 + k] = (__bf16)W2[k * 256 + n];
    }
}

// 512 thr / 8 waves, 1 block/CU.
// Once per block: Y = X_v(20 nodes) * W1A'  -> ldsY (fp32).
// Per tile: GEMM1 = acc(init Y) + x_vp*W1B' (sender K-half only, ldsW+ldsE),
//           epi1 -> ldsH, GEMM2 = H*W2 (32-edge x 64-feat per wave, W2 in regs).
__global__ __launch_bounds__(512, 1) void ec_main(
    const __bf16* __restrict__ nfb,      // [NN][CIN] bf16
    const int*   __restrict__ senders,   // [EE]
    const __bf16* __restrict__ w1g,      // frag-ordered W1'
    const __bf16* __restrict__ w2t,      // [256 n][256 k]
    const float* __restrict__ b1,
    const float* __restrict__ b2,
    float* __restrict__ out)             // [NN][HD] fp32
{
    __shared__ __attribute__((aligned(16))) __bf16 ldsW[32768];    // 64 KB: W1B' (sender) frag-ordered
    __shared__ __attribute__((aligned(16))) __bf16 ldsE[2][8192];  // 2x16 KB: sender rows, frag-ordered
    __shared__ __attribute__((aligned(16))) __bf16 ldsH[16384];    // 32 KB: H, frag-ordered
    __shared__ __attribute__((aligned(16))) float  ldsY[20 * 256]; // 20 KB: per-node receiver partial

    const int tid  = threadIdx.x;
    const int lane = tid & 63;
    const int wave = tid >> 6;           // 0..7
    const int qrow = lane >> 4;
    const int lcol = lane & 15;
    const int blk  = blockIdx.x;
    const int fsl  = wave * 32;          // GEMM1/epi1 feature slice
    const int fs2  = (wave >> 1) * 64;   // GEMM2 feature slice
    const int eh   = wave & 1;           // GEMM2 edge half (node within tile)
    // staging pair ids: pair p = kc*4 + quad
    const int p0 = wave * 2, p1 = wave * 2 + 1;
    const int c0 = p0 >> 2, q0 = p0 & 3;
    const int c1 = p1 >> 2, q1 = p1 & 3;

    // ---- preload all sender indices for this block's 10 tiles ----
    int sidxAll[TPB];
#pragma unroll
    for (int tt = 0; tt < TPB; ++tt)
        sidxAll[tt] = senders[(blk * TPB + tt) * MT + lane];

    // ---- copy W1B' (sender half, w1g chunks 16..31) into ldsW ----
    {
        const float4* src = (const float4*)(w1g + 32768);
        float4* dst = (float4*)ldsW;
#pragma unroll
        for (int i = 0; i < 8; ++i)
            dst[i * 512 + tid] = src[i * 512 + tid];
    }

    // ---- stage tile-0 sender rows into ldsE[0] (async) ----
    gload_lds16(nfb + (size_t)sidxAll[0] * CIN + c0 * 32 + q0 * 8, &ldsE[0][p0 * 512]);
    gload_lds16(nfb + (size_t)sidxAll[0] * CIN + c1 * 32 + q1 * 8, &ldsE[0][p1 * 512]);

    // ---- once per block: Y = X_v * W1A'  (swapped: D = W1A'^T-slice x X_v^T) ----
    {
        f32x4_t ay[2][2];
#pragma unroll
        for (int mi = 0; mi < 2; ++mi)
#pragma unroll
            for (int ni = 0; ni < 2; ++ni)
                ay[mi][ni] = (f32x4_t){0.f, 0.f, 0.f, 0.f};
        bf16x8_t xv[2][4];
#pragma unroll
        for (int ni = 0; ni < 2; ++ni) {
            int ln = ni * 16 + lcol; if (ln > 19) ln = 19;
            const __bf16* row = nfb + (size_t)(blk * 20 + ln) * CIN;
#pragma unroll
            for (int c = 0; c < 4; ++c)
                xv[ni][c] = *(const bf16x8_t*)(row + c * 32 + qrow * 8);
        }
#pragma unroll
        for (int kt = 0; kt < 4; ++kt) {
            bf16x8_t wy[2];
#pragma unroll
            for (int mi = 0; mi < 2; ++mi)
                wy[mi] = *(const bf16x8_t*)(w1g +
                    (size_t)((kt * 4 + qrow) * 256 + fsl + mi * 16 + lcol) * 8);
#pragma unroll
            for (int mi = 0; mi < 2; ++mi)
#pragma unroll
                for (int ni = 0; ni < 2; ++ni)
                    ay[mi][ni] = __builtin_amdgcn_mfma_f32_16x16x32_bf16(
                        wy[mi], xv[ni][kt], ay[mi][ni], 0, 0, 0);
        }
        // C-layout: row = feature fsl+mi*16+qrow*4+r, col = node ni*16+lcol
#pragma unroll
        for (int mi = 0; mi < 2; ++mi)
#pragma unroll
            for (int ni = 0; ni < 2; ++ni) {
                int ln = ni * 16 + lcol;
                if (ln < 20)
                    *(f32x4_t*)(ldsY + ln * 256 + fsl + mi * 16 + qrow * 4) = ay[mi][ni];
            }
    }

    // ---- register-resident W2 slice (64 features): 128 VGPRs ----
    bf16x8_t w2f[8][4];
#pragma unroll
    for (int kt = 0; kt < 8; ++kt)
#pragma unroll
        for (int ni = 0; ni < 4; ++ni)
            w2f[kt][ni] = *(const bf16x8_t*)(w2t + (size_t)(fs2 + ni * 16 + lcol) * 256
                                                 + kt * 32 + qrow * 8);

    float4 bias1[2];
#pragma unroll
    for (int mi = 0; mi < 2; ++mi)
        bias1[mi] = *(const float4*)(b1 + fsl + mi * 16 + qrow * 4);
    float bias2[4];
#pragma unroll
    for (int ni = 0; ni < 4; ++ni)
        bias2[ni] = b2[fs2 + ni * 16 + lcol];

    __syncthreads();   // ldsW + ldsE[0] (vmcnt drained) + ldsY ready

#pragma unroll 1
    for (int t = 0; t < TPB; ++t) {
        const int node0 = (blk * TPB + t) * 2;
        const int cur = t & 1;

        // ---- stage tile t+1 senders into the other ldsE buffer (drains at barrier A,
        //      fully covered by GEMM1) ----
        if (t + 1 < TPB) {
            const __bf16* srow = nfb + (size_t)sidxAll[t + 1] * CIN;
            gload_lds16(srow + c0 * 32 + q0 * 8, &ldsE[1 - cur][p0 * 512]);
            gload_lds16(srow + c1 * 32 + q1 * 8, &ldsE[1 - cur][p1 * 512]);
        }

        // ---- GEMM1: acc init from Y (node-shared), + sender half from ldsW x ldsE ----
        f32x4_t acc[2][4];
#pragma unroll
        for (int mi = 0; mi < 2; ++mi)
#pragma unroll
            for (int ni = 0; ni < 4; ++ni)
                acc[mi][ni] = *(const f32x4_t*)(ldsY + (t * 2 + (ni >> 1)) * 256
                                                + fsl + mi * 16 + qrow * 4);
#pragma unroll
        for (int kt = 0; kt < 4; ++kt) {
            bf16x8_t wf[2], ef[4];
#pragma unroll
            for (int mi = 0; mi < 2; ++mi)
                wf[mi] = *(const bf16x8_t*)(ldsW +
                    (size_t)((kt * 4 + qrow) * 256 + fsl + mi * 16 + lcol) * 8);
#pragma unroll
            for (int ni = 0; ni < 4; ++ni)
                ef[ni] = *(const bf16x8_t*)(&ldsE[cur][0] +
                    (size_t)((kt * 4 + qrow) * 64 + ni * 16 + lcol) * 8);
#pragma unroll
            for (int mi = 0; mi < 2; ++mi)
#pragma unroll
                for (int ni = 0; ni < 4; ++ni)
                    acc[mi][ni] = __builtin_amdgcn_mfma_f32_16x16x32_bf16(
                        wf[mi], ef[ni], acc[mi][ni], 0, 0, 0);
        }

        __syncthreads();   // barrier A: ldsE[cur]/ldsH readers done; staging vmcnt drained

        // ---- epilogue 1: +b1, relu, packed bf16x4 -> ldsH (frag-ordered) ----
#pragma unroll
        for (int mi = 0; mi < 2; ++mi) {
            const int f0  = fsl + mi * 16 + qrow * 4;
            const int ktp = f0 >> 5, qrp = (f0 >> 3) & 3, jh = f0 & 7;
            float4 bb = bias1[mi];
#pragma unroll
            for (int ni = 0; ni < 4; ++ni) {
                int edge = ni * 16 + lcol;
                float v0 = acc[mi][ni][0] + bb.x;
                float v1 = acc[mi][ni][1] + bb.y;
                float v2 = acc[mi][ni][2] + bb.z;
                float v3 = acc[mi][ni][3] + bb.w;
                bf16x4_t h = { (__bf16)fmaxf(v0, 0.f), (__bf16)fmaxf(v1, 0.f),
                               (__bf16)fmaxf(v2, 0.f), (__bf16)fmaxf(v3, 0.f) };
                *(bf16x4_t*)(ldsH + (size_t)((ktp * 4 + qrp) * 64 + edge) * 8 + jh) = h;
            }
        }
        __syncthreads();   // barrier B: ldsH ready

        // ---- GEMM2: D = H(32 edges) x W2(64 features, regs) ----
        f32x4_t acc2[2][4];
#pragma unroll
        for (int mi = 0; mi < 2; ++mi)
#pragma unroll
            for (int ni = 0; ni < 4; ++ni)
                acc2[mi][ni] = (f32x4_t){0.f, 0.f, 0.f, 0.f};
#pragma unroll
        for (int kt = 0; kt < 8; ++kt) {
            bf16x8_t af[2];
#pragma unroll
            for (int mi = 0; mi < 2; ++mi)
                af[mi] = *(const bf16x8_t*)(ldsH +
                    (size_t)((kt * 4 + qrow) * 64 + eh * 32 + mi * 16 + lcol) * 8);
#pragma unroll
            for (int mi = 0; mi < 2; ++mi)
#pragma unroll
                for (int ni = 0; ni < 4; ++ni)
                    acc2[mi][ni] = __builtin_amdgcn_mfma_f32_16x16x32_bf16(
                        af[mi], w2f[kt][ni], acc2[mi][ni], 0, 0, 0);
        }

        // ---- epilogue 2: max over this wave's node (32 edges), +b2, store ----
#pragma unroll
        for (int ni = 0; ni < 4; ++ni) {
            int col = fs2 + ni * 16 + lcol;
            float mx = -3.402823466e38f;
#pragma unroll
            for (int mi = 0; mi < 2; ++mi)
#pragma unroll
                for (int r = 0; r < 4; ++r)
                    mx = fmaxf(mx, acc2[mi][ni][r]);
            mx = fmaxf(mx, __shfl_xor(mx, 16, 64));
            mx = fmaxf(mx, __shfl_xor(mx, 32, 64));
            if (qrow == 0)
                out[(size_t)(node0 + eh) * HD + col] = mx + bias2[ni];
        }
    }
}

extern "C" void kernel_launch(void* const* d_in, const int* in_sizes, int n_in,
                              void* d_out, int out_size, void* d_ws, size_t ws_size,
                              hipStream_t stream) {
    const float* nf      = (const float*)d_in[0];
    const int*   senders = (const int*)d_in[1];
    // d_in[2] = receivers: implicit (repeat(arange(N), K)), unused
    const float* W1 = (const float*)d_in[3];
    const float* b1 = (const float*)d_in[4];
    const float* W2 = (const float*)d_in[5];
    const float* b2 = (const float*)d_in[6];

    __bf16* w1g = (__bf16*)d_ws;                 // 128 KB frag-ordered W1'
    __bf16* w2t = w1g + 256 * 256;               // 128 KB
    __bf16* nfb = w2t + 256 * 256;               // 5.12 MB bf16 node features

    ec_prep<<<(NN * CIN) / 1024 + 256, 256, 0, stream>>>(nf, W1, W2, nfb, w1g, w2t);
    ec_main<<<NBLK, 512, 0, stream>>>(nfb, senders, w1g, w2t, b1, b2, (float*)d_out);
}